// Round 9
// baseline (373.147 us; speedup 1.0000x reference)
//
#include <hip/hip_runtime.h>
#include <hip/hip_bf16.h>

// 8-layer MLP, B=131072, fused. R9: LDS-free row-split design.
//  - R8 post-mortem: R5's LDS act-read pipe (512 b128/CU/layer at structural
//    4-way conflict, 4x cross-wave redundancy) >= MFMA pipe; barrier lockstep
//    makes pipes ADD. R7 (fewer waves) regressed -> occupancy mattered, LDS+
//    barriers stayed.
//  - Fix: each wave owns 32 rows END-TO-END. Acts live in registers as packed
//    bf16 (64 VGPR). Weight pack uses k-slot permutation perm(hi,j)=
//    8*(j>>2)+4*hi+(j&3) applied to BOTH A(weights,pack-side) and B(acts) so
//    each lane's D-output pack order IS the next layer's B-frag order:
//    no cross-lane exchange, no LDS, no barriers, no conflicts.
//  - Weights streamed per wave (identical addresses across waves -> L1
//    broadcast). Layers 0/7 in-lane vs slot-ordered f32 tables.

#define HID 256

typedef __attribute__((ext_vector_type(8))) short bf16x8;
typedef __attribute__((ext_vector_type(8))) unsigned short u16x8;
typedef __attribute__((ext_vector_type(4))) unsigned u32x4;
typedef __attribute__((ext_vector_type(4))) float f32x4;
typedef __attribute__((ext_vector_type(2))) float f32x2;
typedef __attribute__((ext_vector_type(16))) float f32x16;

__device__ __forceinline__ unsigned cvt_pk_bf16(float lo, float hi) {
    unsigned r;
    asm("v_cvt_pk_bf16_f32 %0, %1, %2" : "=v"(r) : "v"(lo), "v"(hi));
    return r;
}
__device__ __forceinline__ float bf_lo(unsigned u) {
    union { unsigned u; float f; } v; v.u = u << 16; return v.f;
}
__device__ __forceinline__ float bf_hi(unsigned u) {
    union { unsigned u; float f; } v; v.u = u & 0xffff0000u; return v.f;
}

struct WPtrs { const float* w[6]; const float* w0; const float* w7; };

// Wp layout (shorts unless noted):
//   [0, 393216)   W1..W6 32x32x16 A-frags, frag (L,fw,kk,ft) at
//                 ((((L*4+fw)*16+kk)*2+ft)*64 + l)*8; elem j =
//                 W_L[64fw+32ft+(l&31)][16kk + 8*(j>>2) + 4*(l>>5) + (j&3)]
//                 (k-slot PERMUTED so B-frag = producer's natural pack order)
//   byte 786432:  w7p f32x4[2][16][8]  {W7[0][f],W7[1][f],W7[2][f],0}
//   byte 790528:  w0p f32x2[2][16][8]  {W0[f][0],W0[f][1]}
//                 both with f = 16kk + 8*(s>>2) + 4*hi + (s&3)
__global__ void pack_w_kernel(WPtrs wp, unsigned short* __restrict__ Wp) {
    int tid = blockIdx.x * 256 + threadIdx.x;
    if (tid < 49152) {
        int l  = tid & 63;
        int ft = (tid >> 6) & 1;
        int kk = (tid >> 7) & 15;
        int fw = (tid >> 11) & 3;
        int L  = tid >> 13;
        int n  = 64 * fw + 32 * ft + (l & 31);
        const float* src = wp.w[L] + n * HID + 16 * kk + 4 * (l >> 5);
        u16x8 v;
#pragma unroll
        for (int j = 0; j < 8; ++j) {
            union { float f; unsigned u; } c; c.f = src[8 * (j >> 2) + (j & 3)];
            unsigned r = c.u + 0x7fffu + ((c.u >> 16) & 1u);  // RNE
            v[j] = (unsigned short)(r >> 16);
        }
        *(u16x8*)(Wp + (size_t)tid * 8) = v;
    } else if (tid < 49408) {
        int t  = tid - 49152;            // w7p slot
        int hi = t >> 7, kk = (t >> 3) & 15, s = t & 7;
        int f  = 16 * kk + 8 * (s >> 2) + 4 * hi + (s & 3);
        float* dst = (float*)((char*)Wp + 786432) + (size_t)t * 4;
        dst[0] = wp.w7[0 * HID + f];
        dst[1] = wp.w7[1 * HID + f];
        dst[2] = wp.w7[2 * HID + f];
        dst[3] = 0.f;
    } else if (tid < 49664) {
        int t  = tid - 49408;            // w0p slot
        int hi = t >> 7, kk = (t >> 3) & 15, s = t & 7;
        int f  = 16 * kk + 8 * (s >> 2) + 4 * hi + (s & 3);
        float* dst = (float*)((char*)Wp + 790528) + (size_t)t * 2;
        dst[0] = wp.w0[2 * f];
        dst[1] = wp.w0[2 * f + 1];
    }
}

// One layer: IN/OUT are 16x u32x4 register arrays (granule-major packed bf16).
// Chunk C computes out-features [32C,32C+32) via 16 chained MFMAs; the D
// accumulator's reg order maps 1:1 to the packed output order (see pack note).
template<int LBASE>
__device__ __forceinline__ void layer_body(const unsigned short* wlane,
                                           const u32x4* IN, u32x4* OUT) {
#pragma unroll
    for (int C = 0; C < 8; ++C) {
        f32x16 acc;
#pragma unroll
        for (int j = 0; j < 16; ++j) acc[j] = 0.f;
#pragma unroll
        for (int kk = 0; kk < 16; ++kk) {
            const int fidx = (((C >> 1) * 16 + kk) * 2 + (C & 1));
            bf16x8 wf = *(const bf16x8*)(wlane + (size_t)LBASE * 65536 + fidx * 512);
            bf16x8 af = *(const bf16x8*)(&IN[kk]);
            acc = __builtin_amdgcn_mfma_f32_32x32x16_bf16(wf, af, acc, 0, 0, 0);
        }
        u32x4 o0, o1;
#pragma unroll
        for (int t = 0; t < 4; ++t) {
            o0[t] = cvt_pk_bf16(fmaxf(0.f, acc[2 * t]),     fmaxf(0.f, acc[2 * t + 1]));
            o1[t] = cvt_pk_bf16(fmaxf(0.f, acc[8 + 2 * t]), fmaxf(0.f, acc[8 + 2 * t + 1]));
        }
        OUT[2 * C]     = o0;   // granule 2C   (features 32C+{0..15} slot-order)
        OUT[2 * C + 1] = o1;   // granule 2C+1
    }
}

__launch_bounds__(256, 2)
__global__ void mlp_fused_kernel(const float* __restrict__ x,
                                 const unsigned short* __restrict__ Wp,
                                 float* __restrict__ out) {
    const int tid = threadIdx.x;
    const int l   = tid & 63;
    const int wv  = tid >> 6;
    const int hi  = l >> 5;
    const long row = (long)blockIdx.x * 128 + wv * 32 + (l & 31);

    const unsigned short* wlane = Wp + (size_t)l * 8;

    // ---- layer 0: per-lane, slot-ordered w0p table ----
    f32x2 xv = *(const f32x2*)(x + row * 2);
    const float* w0p = (const float*)((const char*)Wp + 790528) + hi * 256;
    u32x4 U[16], O[16];
#pragma unroll
    for (int kk = 0; kk < 16; ++kk) {
        u32x4 g;
#pragma unroll
        for (int t = 0; t < 4; ++t) {
            f32x4 wq = *(const f32x4*)(w0p + kk * 16 + 4 * t);  // slots 2t,2t+1
            float h0 = fmaf(xv[0], wq[0], xv[1] * wq[1]);
            float h1 = fmaf(xv[0], wq[2], xv[1] * wq[3]);
            g[t] = cvt_pk_bf16(fmaxf(0.f, h0), fmaxf(0.f, h1));
        }
        U[kk] = g;
    }

    // ---- layers 1..6: register-resident, no LDS, no barriers ----
    layer_body<0>(wlane, U, O);
    layer_body<1>(wlane, O, U);
    layer_body<2>(wlane, U, O);
    layer_body<3>(wlane, O, U);
    layer_body<4>(wlane, U, O);
    layer_body<5>(wlane, O, U);     // final acts in U

    // ---- layer 7: per-lane partial dot over this lane's 128 features ----
    const float* w7p = (const float*)((const char*)Wp + 786432) + hi * 512;
    float a0 = 0.f, a1 = 0.f, a2 = 0.f;
#pragma unroll
    for (int kk = 0; kk < 16; ++kk) {
        u32x4 g = U[kk];
#pragma unroll
        for (int idx = 0; idx < 4; ++idx) {
            unsigned u = g[idx];
            float hlo = bf_lo(u), hhi = bf_hi(u);
            f32x4 wA = *(const f32x4*)(w7p + (kk * 8 + 2 * idx) * 4);
            f32x4 wB = *(const f32x4*)(w7p + (kk * 8 + 2 * idx + 1) * 4);
            a0 = fmaf(hlo, wA[0], fmaf(hhi, wB[0], a0));
            a1 = fmaf(hlo, wA[1], fmaf(hhi, wB[1], a1));
            a2 = fmaf(hlo, wA[2], fmaf(hhi, wB[2], a2));
        }
    }
    // combine the two feature-halves of each row (lanes l and l+32)
    a0 += __shfl_xor(a0, 32);
    a1 += __shfl_xor(a1, 32);
    a2 += __shfl_xor(a2, 32);
    if (l < 32) {
        long o = row * 3;
        out[o + 0] = 1.f / (1.f + __expf(-a0));
        out[o + 1] = 1.f / (1.f + __expf(-a1));
        out[o + 2] = 1.f / (1.f + __expf(-a2));
    }
}

extern "C" void kernel_launch(void* const* d_in, const int* in_sizes, int n_in,
                              void* d_out, int out_size, void* d_ws, size_t ws_size,
                              hipStream_t stream) {
    const float* x = (const float*)d_in[0];
    WPtrs wp;
    wp.w0 = (const float*)d_in[1];
    for (int i = 0; i < 6; ++i) wp.w[i] = (const float*)d_in[2 + i];
    wp.w7 = (const float*)d_in[8];
    float* out = (float*)d_out;
    unsigned short* Wp = (unsigned short*)d_ws;   // 792,576 B used

    pack_w_kernel<<<194, 256, 0, stream>>>(wp, Wp);
    mlp_fused_kernel<<<1024, 256, 0, stream>>>(x, Wp, out);
}

// Round 10
// 188.365 us; speedup vs baseline: 1.9810x; 1.9810x over previous
//
#include <hip/hip_runtime.h>
#include <hip/hip_bf16.h>

// 8-layer MLP, B=131072, fused. R10 vs R5:
//  - R9 post-mortem: all-register design fails (serial MFMA chains, 13% util).
//  - R5 diagnosis: per-wave MFMA duty 128cyc-issue/250cyc-loop = 51% == the
//    measured 46-48% MfmaUtil. Waves can't cover each other: R5 sits at the
//    128-reg/16-wave cliff (60 VGPR + 64 AGPR = 124/128) -> compiler has no
//    headroom to pipeline ds_reads or deepen the weight ring. R7 bought regs
//    with occupancy -> worse.
//  - Fix: halve acc. Wave tile 32r x 64f (acc = 2 frags = 32 AGPR), BM=64,
//    512 thr, 8 waves = 2 row-groups x 4 feature-slices, 2 blocks/CU (16
//    waves, same occupancy as R5). Freed ~32 regs -> depth-2 weight ring
//    (static slots via full unroll) + compiler ds_read pipelining slack.
//    Act-LDS traffic per CU also halves.

#define HID 256
#define BM 64
#define NBLK 2048      // 131072 / 64
#define HPITCH 264

typedef __attribute__((ext_vector_type(8))) short bf16x8;
typedef __attribute__((ext_vector_type(8))) unsigned short u16x8;
typedef __attribute__((ext_vector_type(4))) unsigned short u16x4;
typedef __attribute__((ext_vector_type(4))) float f32x4;
typedef __attribute__((ext_vector_type(16))) float f32x16;

__device__ __forceinline__ unsigned cvt_pk_bf16(float lo, float hi) {
    unsigned r;
    asm("v_cvt_pk_bf16_f32 %0, %1, %2" : "=v"(r) : "v"(lo), "v"(hi));
    return r;
}

struct WPtrs { const float* w[6]; const float* w7; };

// Pack W1..W6 as 32x32x16 A-frags (unchanged from R5, verified):
//   frag (L,fw,kk,ft): lane l, elem j = W_L[64fw+32ft+(l&31)][16kk+8(l>>5)+j]
//   at Wp[(((L*4+fw)*16+kk)*2+ft)*64*8 + l*8]
// W7 as 16x16x32 A-frags (rows 3..15 zero) at Wp+393216.
__global__ void pack_w_kernel(WPtrs wp, unsigned short* __restrict__ Wp) {
    int tid = blockIdx.x * 256 + threadIdx.x;
    if (tid < 49152) {
        int l  = tid & 63;
        int ft = (tid >> 6) & 1;
        int kk = (tid >> 7) & 15;
        int fw = (tid >> 11) & 3;
        int L  = tid >> 13;
        int n  = 64 * fw + 32 * ft + (l & 31);
        int k0 = 16 * kk + 8 * (l >> 5);
        const float* src = wp.w[L] + n * HID + k0;
        u16x8 v;
#pragma unroll
        for (int j = 0; j < 8; ++j) {
            union { float f; unsigned u; } c; c.f = src[j];
            unsigned r = c.u + 0x7fffu + ((c.u >> 16) & 1u);  // RNE
            v[j] = (unsigned short)(r >> 16);
        }
        *(u16x8*)(Wp + (size_t)tid * 8) = v;
    } else if (tid < 49664) {
        int t  = tid - 49152;
        int l  = t & 63;
        int kk = t >> 6;                 // 0..7
        int n  = l & 15;
        int k0 = 32 * kk + 8 * (l >> 4);
        u16x8 v;
#pragma unroll
        for (int j = 0; j < 8; ++j) {
            unsigned short s = 0;
            if (n < 3) {
                union { float f; unsigned u; } c; c.f = wp.w7[n * HID + k0 + j];
                s = (unsigned short)((c.u + 0x7fffu + ((c.u >> 16) & 1u)) >> 16);
            }
            v[j] = s;
        }
        *(u16x8*)(Wp + 393216 + (size_t)t * 8) = v;
    }
}

__launch_bounds__(512, 4)
__global__ void mlp_fused_kernel(const float* __restrict__ x,
                                 const float* __restrict__ W0,
                                 const unsigned short* __restrict__ Wp,
                                 float* __restrict__ out) {
    __shared__ __align__(16) unsigned short Hs[BM][HPITCH];  // 33,792 B
    __shared__ __align__(16) float Ps[4][BM][4];             // 4,096 B
    __shared__ float xsf[2 * BM];                            // 512 B

    const int tid = threadIdx.x;
    const int l   = tid & 63;
    const int w   = tid >> 6;        // 0..7
    const int fs  = w & 3;           // feature slice [64fs, 64fs+64)
    const int rg  = w >> 2;          // row group: rows [32rg, 32rg+32)
    const long r0 = (long)blockIdx.x * BM;

    const unsigned short* wbl = Wp + (size_t)fs * 16384 + (size_t)l * 8;

    // depth-2 weight ring: slot g%3 holds frags for step g = 16L+kk
    bf16x8 wb[3][2];
    wb[0][0] = *(const bf16x8*)(wbl);
    wb[0][1] = *(const bf16x8*)(wbl + 512);
    wb[1][0] = *(const bf16x8*)(wbl + 1024);
    wb[1][1] = *(const bf16x8*)(wbl + 1536);

    // ---- stage x ----
    if (tid < 2 * BM) xsf[tid] = x[r0 * 2 + tid];
    const int fp = (tid & 127) * 2;          // feature pair
    const int q  = tid >> 7;                 // row quarter (16 rows each)
    f32x4 w0v = *(const f32x4*)(W0 + 2 * fp);
    __syncthreads();

    // ---- layer 0: relu(x @ W0.T) -> bf16 Hs ----
#pragma unroll
    for (int i = 0; i < 16; ++i) {
        int m = 16 * q + i;
        float x0 = xsf[2 * m], x1 = xsf[2 * m + 1];
        float ha = fmaf(x0, w0v[0], x1 * w0v[1]);
        float hb = fmaf(x0, w0v[2], x1 * w0v[3]);
        *(unsigned*)(&Hs[m][fp]) = cvt_pk_bf16(fmaxf(0.f, ha), fmaxf(0.f, hb));
    }
    __syncthreads();

    // ---- layers 1..6: 32x32x16 MFMA; wave (rg,fs): rows [32rg,32rg+32),
    //      features [64fs, 64fs+64) ----
    const int c  = l & 31;
    const int hi = l >> 5;
#pragma unroll
    for (int L = 0; L < 6; ++L) {
        f32x16 acc[2];     // [ft] -- 32 AGPR total
#pragma unroll
        for (int ft = 0; ft < 2; ++ft)
#pragma unroll
            for (int j = 0; j < 16; ++j) acc[ft][j] = 0.f;

#pragma unroll
        for (int kk = 0; kk < 16; ++kk) {
            const int g   = 16 * L + kk;
            const int cur = g % 3;
            const int pre = (g + 2) % 3;
            if (g + 2 < 96) {     // prefetch step g+2 (crosses layer boundary)
                const int gl = (g + 2) >> 4, gk = (g + 2) & 15;
                wb[pre][0] = *(const bf16x8*)(wbl + gl * 65536 + gk * 1024);
                wb[pre][1] = *(const bf16x8*)(wbl + gl * 65536 + gk * 1024 + 512);
            }
            bf16x8 a0 = *(const bf16x8*)(&Hs[32 * rg + c][16 * kk + 8 * hi]);
            acc[0] = __builtin_amdgcn_mfma_f32_32x32x16_bf16(wb[cur][0], a0, acc[0], 0, 0, 0);
            acc[1] = __builtin_amdgcn_mfma_f32_32x32x16_bf16(wb[cur][1], a0, acc[1], 0, 0, 0);
        }
        __syncthreads();   // all Hs reads done; overwrite in place
        // D: lane holds batch row 32rg+c, features 64fs+32ft+8g2+4hi+{0..3}
#pragma unroll
        for (int ft = 0; ft < 2; ++ft) {
            f32x16 v = acc[ft];
#pragma unroll
            for (int g2 = 0; g2 < 4; ++g2) {
                union { unsigned u[2]; u16x4 s; } pk;
                pk.u[0] = cvt_pk_bf16(fmaxf(0.f, v[4 * g2]),     fmaxf(0.f, v[4 * g2 + 1]));
                pk.u[1] = cvt_pk_bf16(fmaxf(0.f, v[4 * g2 + 2]), fmaxf(0.f, v[4 * g2 + 3]));
                *(u16x4*)(&Hs[32 * rg + c][64 * fs + 32 * ft + 8 * g2 + 4 * hi]) = pk.s;
            }
        }
        __syncthreads();
    }

    // ---- layer 7 (16x16x32): wave (rg,fs) -> rows [32rg,32rg+32),
    //      K slices {2fs, 2fs+1} ----
    const int lr = l & 15, lg = l >> 4;
    const unsigned short* w7b = Wp + 393216 + (size_t)l * 8;
    bf16x8 w7f0 = *(const bf16x8*)(w7b + (2 * fs) * 512);
    bf16x8 w7f1 = *(const bf16x8*)(w7b + (2 * fs + 1) * 512);
    f32x4 acc7[2];
#pragma unroll
    for (int mt = 0; mt < 2; ++mt) acc7[mt] = (f32x4){0.f, 0.f, 0.f, 0.f};
#pragma unroll
    for (int mt = 0; mt < 2; ++mt) {
        bf16x8 a = *(const bf16x8*)(&Hs[32 * rg + 16 * mt + lr][32 * (2 * fs) + 8 * lg]);
        acc7[mt] = __builtin_amdgcn_mfma_f32_16x16x32_bf16(w7f0, a, acc7[mt], 0, 0, 0);
        bf16x8 b = *(const bf16x8*)(&Hs[32 * rg + 16 * mt + lr][32 * (2 * fs + 1) + 8 * lg]);
        acc7[mt] = __builtin_amdgcn_mfma_f32_16x16x32_bf16(w7f1, b, acc7[mt], 0, 0, 0);
    }
    if (lg == 0) {
#pragma unroll
        for (int mt = 0; mt < 2; ++mt)
            *(f32x4*)(&Ps[fs][32 * rg + 16 * mt + lr][0]) = acc7[mt];
    }
    __syncthreads();
    // ---- reduce 4 K-partials + sigmoid ----
    if (tid < 3 * BM) {
        int row = tid / 3, o = tid - 3 * row;
        float s = Ps[0][row][o] + Ps[1][row][o] + Ps[2][row][o] + Ps[3][row][o];
        out[r0 * 3 + tid] = 1.f / (1.f + __expf(-s));
    }
}

extern "C" void kernel_launch(void* const* d_in, const int* in_sizes, int n_in,
                              void* d_out, int out_size, void* d_ws, size_t ws_size,
                              hipStream_t stream) {
    const float* x  = (const float*)d_in[0];
    const float* W0 = (const float*)d_in[1];
    WPtrs wp;
    for (int i = 0; i < 6; ++i) wp.w[i] = (const float*)d_in[2 + i];
    wp.w7 = (const float*)d_in[8];
    float* out = (float*)d_out;
    unsigned short* Wp = (unsigned short*)d_ws;   // 794,624 B used

    pack_w_kernel<<<194, 256, 0, stream>>>(wp, Wp);
    mlp_fused_kernel<<<NBLK, 512, 0, stream>>>(x, W0, Wp, out);
}